// Round 1
// baseline (276.356 us; speedup 1.0000x reference)
//
#include <hip/hip_runtime.h>
#include <hip/hip_bf16.h>

typedef float  f32x4  __attribute__((ext_vector_type(4)));
typedef short  bf16x8 __attribute__((ext_vector_type(8)));
typedef short  s16x4  __attribute__((ext_vector_type(4)));
typedef unsigned int u32x4 __attribute__((ext_vector_type(4)));

#define MFMA_BF16 __builtin_amdgcn_mfma_f32_16x16x32_bf16

__device__ __forceinline__ short f2bf(float f) {
  union { float f; unsigned u; } x; x.f = f;
  unsigned r = x.u + 0x7FFFu + ((x.u >> 16) & 1u);
  return (short)(r >> 16);
}

constexpr int S = 2048, D = 1024, H = 16, HD = 64;
constexpr float SCALE = 0.125f;           // 1/sqrt(64)
constexpr float L2E = 1.44269504f;

// ---------------------------------------------------------------------------
// Fused flash attention with bias.
// Block: 256 threads (4 waves). Each block: one (b, h, 64 query rows).
// Each wave owns 16 query rows. Swapped QK^T: S^T = K * Q^T so each lane
// holds a full slice of one query's row of P; softmax reduce is
// shfl_xor(16/32). PV computed as O^T = V^T * P^T; P^T B-fragment comes
// directly from S^T D-registers (no cross-lane movement).
// ---------------------------------------------------------------------------
__global__ __launch_bounds__(256, 2)
void attn_fused(const float* __restrict__ Qg, const float* __restrict__ Kg,
                const float* __restrict__ Vg, const float* __restrict__ Bg,
                short* __restrict__ comb) {
  constexpr int KST = 68;   // K/Vt LDS row stride (bf16 elems): 136B, 8B-aligned, 2-way max conflict
  constexpr int BST = 68;   // bias LDS row stride (f32)
  const int q0 = blockIdx.x * 64;
  const int h  = blockIdx.y;
  const int b  = blockIdx.z;
  const int t  = threadIdx.x;
  const int lane = t & 63, w = t >> 6;
  const int lg = lane >> 4, lm = lane & 15;

  __shared__ __attribute__((aligned(16))) short k_lds[64 * KST];
  __shared__ __attribute__((aligned(16))) short vt_lds[64 * KST];
  __shared__ __attribute__((aligned(16))) float bias_lds[64 * BST]; // reused as out staging

  const f32x4 zero4 = {0.f, 0.f, 0.f, 0.f};

  // Q fragment (B operand of S^T = K*Q^T): lane holds query col q = w*16+lm
  bf16x8 qf[2];
  {
    const float* qp = Qg + ((size_t)(b * S + q0 + w * 16 + lm)) * D + h * HD;
    #pragma unroll
    for (int kk = 0; kk < 2; ++kk)
      #pragma unroll
      for (int j = 0; j < 8; ++j)
        qf[kk][j] = f2bf(qp[kk * 32 + (j >> 2) * 16 + lg * 4 + (j & 3)]);
  }

  f32x4 o[4];   // O^T accum: col q = lm, row d = of*16 + lg*4 + j
  #pragma unroll
  for (int i = 0; i < 4; ++i) o[i] = zero4;
  float M = -__builtin_inff(), L = 0.f;

  const float* kp0 = Kg + ((size_t)b * S) * D + h * HD;
  const float* vp0 = Vg + ((size_t)b * S) * D + h * HD;
  const float* bp0 = Bg + ((size_t)(h * S + q0)) * S;

  for (int kv0 = 0; kv0 < S; kv0 += 64) {
    __syncthreads();
    // ---- cooperative staging: K tile, V^T tile (bf16), bias tile (f32) ----
    {
      const float* kp = kp0 + (size_t)kv0 * D;
      const float* vp = vp0 + (size_t)kv0 * D;
      const float* bp = bp0 + kv0;
      #pragma unroll
      for (int i = 0; i < 4; ++i) {
        int idx = i * 256 + t;          // 1024 float4 chunks = 64x64 f32
        int r  = idx >> 4;              // tile row
        int c4 = (idx & 15) * 4;        // tile col
        float4 kv4 = *(const float4*)(kp + (size_t)r * D + c4);
        s16x4 ks; ks[0]=f2bf(kv4.x); ks[1]=f2bf(kv4.y); ks[2]=f2bf(kv4.z); ks[3]=f2bf(kv4.w);
        *(s16x4*)&k_lds[r * KST + c4] = ks;
        float4 vv4 = *(const float4*)(vp + (size_t)r * D + c4);
        vt_lds[(c4 + 0) * KST + r] = f2bf(vv4.x);
        vt_lds[(c4 + 1) * KST + r] = f2bf(vv4.y);
        vt_lds[(c4 + 2) * KST + r] = f2bf(vv4.z);
        vt_lds[(c4 + 3) * KST + r] = f2bf(vv4.w);
        float4 bb4 = *(const float4*)(bp + (size_t)r * S + c4);
        *(float4*)&bias_lds[r * BST + c4] = bb4;
      }
    }
    __syncthreads();

    // ---- S^T = K * Q^T : rows kv (4 frags of 16), cols q (16 per wave) ----
    f32x4 sacc[4];
    #pragma unroll
    for (int i = 0; i < 4; ++i) sacc[i] = zero4;
    #pragma unroll
    for (int kk = 0; kk < 2; ++kk) {
      #pragma unroll
      for (int mf = 0; mf < 4; ++mf) {
        const short* kr = &k_lds[(mf * 16 + lm) * KST + kk * 32 + lg * 4];
        s16x4 c0 = *(const s16x4*)(kr);
        s16x4 c1 = *(const s16x4*)(kr + 16);
        bf16x8 a;
        a[0]=c0[0]; a[1]=c0[1]; a[2]=c0[2]; a[3]=c0[3];
        a[4]=c1[0]; a[5]=c1[1]; a[6]=c1[2]; a[7]=c1[3];
        sacc[mf] = MFMA_BF16(a, qf[kk], sacc[mf], 0, 0, 0);
      }
    }

    // ---- online softmax (bias added to raw logits, THEN scaled) ----
    float p[4][4];
    float tmax = -__builtin_inff();
    #pragma unroll
    for (int mf = 0; mf < 4; ++mf)
      #pragma unroll
      for (int j = 0; j < 4; ++j) {
        float tv = (sacc[mf][j] +
                    bias_lds[(w * 16 + lm) * BST + mf * 16 + lg * 4 + j]) * SCALE;
        p[mf][j] = tv;
        tmax = fmaxf(tmax, tv);
      }
    tmax = fmaxf(tmax, __shfl_xor(tmax, 16, 64));
    tmax = fmaxf(tmax, __shfl_xor(tmax, 32, 64));
    const float Mn = fmaxf(M, tmax);
    const float alpha = exp2f((M - Mn) * L2E);
    float psum = 0.f;
    #pragma unroll
    for (int mf = 0; mf < 4; ++mf)
      #pragma unroll
      for (int j = 0; j < 4; ++j) {
        float e = exp2f((p[mf][j] - Mn) * L2E);
        p[mf][j] = e;
        psum += e;
      }
    psum += __shfl_xor(psum, 16, 64);
    psum += __shfl_xor(psum, 32, 64);
    L = L * alpha + psum;
    M = Mn;
    #pragma unroll
    for (int of = 0; of < 4; ++of) {
      o[of][0] *= alpha; o[of][1] *= alpha; o[of][2] *= alpha; o[of][3] *= alpha;
    }

    // ---- P^T B-fragments straight from S^T D-register layout ----
    bf16x8 pb[2];
    #pragma unroll
    for (int kk = 0; kk < 2; ++kk)
      #pragma unroll
      for (int j = 0; j < 8; ++j)
        pb[kk][j] = f2bf(p[kk * 2 + (j >> 2)][j & 3]);

    // ---- O^T += V^T * P^T ----
    #pragma unroll
    for (int kk = 0; kk < 2; ++kk) {
      #pragma unroll
      for (int of = 0; of < 4; ++of) {
        const short* vr = &vt_lds[(of * 16 + lm) * KST + kk * 32 + lg * 4];
        s16x4 c0 = *(const s16x4*)(vr);
        s16x4 c1 = *(const s16x4*)(vr + 16);
        bf16x8 a;
        a[0]=c0[0]; a[1]=c0[1]; a[2]=c0[2]; a[3]=c0[3];
        a[4]=c1[0]; a[5]=c1[1]; a[6]=c1[2]; a[7]=c1[3];
        o[of] = MFMA_BF16(a, pb[kk], o[of], 0, 0, 0);
      }
    }
  }

  // ---- normalize, transpose O^T -> [q][d] through LDS, coalesced bf16 store ----
  const float invL = 1.f / L;
  __syncthreads();                       // all waves done with bias_lds
  short* out_lds = (short*)bias_lds;     // [64 q][64 d], stride 72 (144B rows)
  #pragma unroll
  for (int of = 0; of < 4; ++of)
    #pragma unroll
    for (int j = 0; j < 4; ++j)
      out_lds[(w * 16 + lm) * 72 + of * 16 + lg * 4 + j] = f2bf(o[of][j] * invL);
  __syncthreads();
  #pragma unroll
  for (int it = 0; it < 2; ++it) {
    int idx = it * 256 + t;
    int r = idx >> 3, seg = idx & 7;
    u32x4 u = *(const u32x4*)&out_lds[r * 72 + seg * 8];
    *(u32x4*)&comb[((size_t)(b * S + q0 + r)) * D + h * HD + seg * 8] = u;
  }
}

// ---------------------------------------------------------------------------
// w_out [k][n] f32  ->  Wt [n][k] bf16 (so GEMM B-fragments read contiguous k)
// ---------------------------------------------------------------------------
__global__ __launch_bounds__(256)
void wt_kernel(const float* __restrict__ W, short* __restrict__ Wt) {
  __shared__ __attribute__((aligned(16))) short tile[64 * 72];
  const int n0 = blockIdx.x * 64, k0 = blockIdx.y * 64;
  const int t = threadIdx.x;
  #pragma unroll
  for (int i = 0; i < 4; ++i) {
    int idx = i * 256 + t;
    int r  = idx >> 4;          // k row
    int c4 = (idx & 15) * 4;    // n col
    float4 wv = *(const float4*)(W + (size_t)(k0 + r) * D + n0 + c4);
    tile[(c4 + 0) * 72 + r] = f2bf(wv.x);
    tile[(c4 + 1) * 72 + r] = f2bf(wv.y);
    tile[(c4 + 2) * 72 + r] = f2bf(wv.z);
    tile[(c4 + 3) * 72 + r] = f2bf(wv.w);
  }
  __syncthreads();
  #pragma unroll
  for (int it = 0; it < 2; ++it) {
    int idx = it * 256 + t;
    int r = idx >> 3, seg = idx & 7;
    u32x4 u = *(const u32x4*)&tile[r * 72 + seg * 8];
    *(u32x4*)&Wt[(size_t)(n0 + r) * D + k0 + seg * 8] = u;
  }
}

// ---------------------------------------------------------------------------
// C[4096,1024] f32 = A[4096,1024] bf16 * Wt^T ; Wt is [n][k] bf16.
// 128x128 tile, BK=64, 4 waves (2x2), 4x4 16x16 frags per wave.
// ---------------------------------------------------------------------------
__global__ __launch_bounds__(256, 2)
void proj_gemm(const short* __restrict__ A, const short* __restrict__ Bt,
               float* __restrict__ C) {
  constexpr int AST = 80;   // 160B rows: 16B-aligned stores, 4-way read conflict max
  __shared__ __attribute__((aligned(16))) short a_lds[128 * AST];
  __shared__ __attribute__((aligned(16))) short b_lds[128 * AST];
  const int m0 = blockIdx.x * 128, n0 = blockIdx.y * 128;
  const int t = threadIdx.x, lane = t & 63, w = t >> 6;
  const int lg = lane >> 4, lm = lane & 15;
  const int wm = w >> 1, wn = w & 1;

  const f32x4 zero4 = {0.f, 0.f, 0.f, 0.f};
  f32x4 acc[4][4];
  #pragma unroll
  for (int i = 0; i < 4; ++i)
    #pragma unroll
    for (int j = 0; j < 4; ++j) acc[i][j] = zero4;

  for (int kt = 0; kt < D; kt += 64) {
    __syncthreads();
    #pragma unroll
    for (int i = 0; i < 4; ++i) {
      int idx = i * 256 + t;        // 1024 chunks of 8 bf16 = 128x64
      int r = idx >> 3, seg = idx & 7;
      u32x4 av = *(const u32x4*)&A [(size_t)(m0 + r) * D + kt + seg * 8];
      *(u32x4*)&a_lds[r * AST + seg * 8] = av;
      u32x4 bv = *(const u32x4*)&Bt[(size_t)(n0 + r) * D + kt + seg * 8];
      *(u32x4*)&b_lds[r * AST + seg * 8] = bv;
    }
    __syncthreads();
    #pragma unroll
    for (int kk = 0; kk < 2; ++kk) {
      bf16x8 af[4], bfr[4];
      #pragma unroll
      for (int mf = 0; mf < 4; ++mf) {
        const short* ar = &a_lds[(wm * 64 + mf * 16 + lm) * AST + kk * 32 + lg * 4];
        s16x4 c0 = *(const s16x4*)(ar);
        s16x4 c1 = *(const s16x4*)(ar + 16);
        af[mf][0]=c0[0]; af[mf][1]=c0[1]; af[mf][2]=c0[2]; af[mf][3]=c0[3];
        af[mf][4]=c1[0]; af[mf][5]=c1[1]; af[mf][6]=c1[2]; af[mf][7]=c1[3];
      }
      #pragma unroll
      for (int nf = 0; nf < 4; ++nf) {
        const short* br = &b_lds[(wn * 64 + nf * 16 + lm) * AST + kk * 32 + lg * 4];
        s16x4 c0 = *(const s16x4*)(br);
        s16x4 c1 = *(const s16x4*)(br + 16);
        bfr[nf][0]=c0[0]; bfr[nf][1]=c0[1]; bfr[nf][2]=c0[2]; bfr[nf][3]=c0[3];
        bfr[nf][4]=c1[0]; bfr[nf][5]=c1[1]; bfr[nf][6]=c1[2]; bfr[nf][7]=c1[3];
      }
      #pragma unroll
      for (int mf = 0; mf < 4; ++mf)
        #pragma unroll
        for (int nf = 0; nf < 4; ++nf)
          acc[mf][nf] = MFMA_BF16(af[mf], bfr[nf], acc[mf][nf], 0, 0, 0);
    }
  }
  #pragma unroll
  for (int mf = 0; mf < 4; ++mf)
    #pragma unroll
    for (int j = 0; j < 4; ++j)
      #pragma unroll
      for (int nf = 0; nf < 4; ++nf)
        C[(size_t)(m0 + wm * 64 + mf * 16 + lg * 4 + j) * D +
          n0 + wn * 64 + nf * 16 + lm] = acc[mf][nf][j];
}

extern "C" void kernel_launch(void* const* d_in, const int* in_sizes, int n_in,
                              void* d_out, int out_size, void* d_ws, size_t ws_size,
                              hipStream_t stream) {
  const float* Qg = (const float*)d_in[0];
  const float* Kg = (const float*)d_in[1];
  const float* Vg = (const float*)d_in[2];
  const float* Bg = (const float*)d_in[3];
  const float* Wg = (const float*)d_in[4];
  float* out = (float*)d_out;

  short* comb = (short*)d_ws;                       // [4096][1024] bf16 = 8 MB
  short* Wt   = comb + (size_t)(2 * S) * D;         // [1024][1024] bf16 = 2 MB

  attn_fused<<<dim3(S / 64, H, 2), 256, 0, stream>>>(Qg, Kg, Vg, Bg, comb);
  wt_kernel<<<dim3(D / 64, D / 64), 256, 0, stream>>>(Wg, Wt);
  proj_gemm<<<dim3((2 * S) / 128, D / 128), 256, 0, stream>>>(comb, Wt, out);
}

// Round 2
// 179.122 us; speedup vs baseline: 1.5428x; 1.5428x over previous
//
#include <hip/hip_runtime.h>

typedef float  f32x4  __attribute__((ext_vector_type(4)));
typedef short  bf16x8 __attribute__((ext_vector_type(8)));
typedef short  s16x4  __attribute__((ext_vector_type(4)));
typedef unsigned int u32x4 __attribute__((ext_vector_type(4)));

#define MFMA_BF16 __builtin_amdgcn_mfma_f32_16x16x32_bf16

__device__ __forceinline__ short f2bf(float f) {
  union { float f; unsigned u; } x; x.f = f;
  unsigned r = x.u + 0x7FFFu + ((x.u >> 16) & 1u);
  return (short)(r >> 16);
}

constexpr int S = 2048, D = 1024, H = 16, HD = 64;
constexpr int NT = S / 64;                 // 32 kv tiles
constexpr float SCALE = 0.125f;            // 1/sqrt(64)
constexpr float L2E = 1.44269504f;
constexpr float SL = SCALE * L2E;          // logits -> log2 domain in one mul

// async 16B global->LDS (lds dest must be wave-uniform; HW adds lane*16)
#define GLDS16(g, l) __builtin_amdgcn_global_load_lds( \
    (const __attribute__((address_space(1))) unsigned*)(g), \
    (__attribute__((address_space(3))) unsigned*)(l), 16, 0, 0)

// ---------------------------------------------------------------------------
// K/V prep: f32 [B,S,D] head-slices -> bf16 fragment-major tiles.
// Per (b,h,kv-tile): 8 K-frags (f=kk*4+mf) and 8 V^T-frags (f=kk*4+of),
// each frag = 64 lanes x 8 bf16 contiguous -> tile block = 4096 shorts (8KB).
// ---------------------------------------------------------------------------
__global__ __launch_bounds__(256)
void kv_prep(const float* __restrict__ Kg, const float* __restrict__ Vg,
             short* __restrict__ Kb, short* __restrict__ Vb) {
  const int tile = blockIdx.x, h = blockIdx.y, b = blockIdx.z;
  const int t = threadIdx.x, lane = t & 63, w = t >> 6;
  const int lg = lane >> 4, lm = lane & 15;
  __shared__ short kt[64 * 68], vt[64 * 68];
  const float* kp = Kg + ((size_t)(b * S + tile * 64)) * D + h * HD;
  const float* vp = Vg + ((size_t)(b * S + tile * 64)) * D + h * HD;
  #pragma unroll
  for (int i = 0; i < 4; ++i) {
    int idx = i * 256 + t, r = idx >> 4, c4 = (idx & 15) * 4;
    float4 k4 = *(const float4*)(kp + (size_t)r * D + c4);
    s16x4 ks; ks[0]=f2bf(k4.x); ks[1]=f2bf(k4.y); ks[2]=f2bf(k4.z); ks[3]=f2bf(k4.w);
    *(s16x4*)&kt[r * 68 + c4] = ks;
    float4 v4 = *(const float4*)(vp + (size_t)r * D + c4);
    s16x4 vs; vs[0]=f2bf(v4.x); vs[1]=f2bf(v4.y); vs[2]=f2bf(v4.z); vs[3]=f2bf(v4.w);
    *(s16x4*)&vt[r * 68 + c4] = vs;
  }
  __syncthreads();
  const size_t obase = ((size_t)((b * H + h) * NT + tile)) * 4096;
  #pragma unroll
  for (int j = 0; j < 2; ++j) {          // K frags: elems K[mf*16+lm][kk*32+lg*4 +0..3, +16..19]
    int f = w + j * 4, kk = f >> 2, mf = f & 3;
    int row = mf * 16 + lm, col = kk * 32 + lg * 4;
    s16x4 c0 = *(const s16x4*)&kt[row * 68 + col];
    s16x4 c1 = *(const s16x4*)&kt[row * 68 + col + 16];
    bf16x8 a;
    a[0]=c0[0]; a[1]=c0[1]; a[2]=c0[2]; a[3]=c0[3];
    a[4]=c1[0]; a[5]=c1[1]; a[6]=c1[2]; a[7]=c1[3];
    *(bf16x8*)&Kb[obase + (size_t)(f * 64 + lane) * 8] = a;
  }
  #pragma unroll
  for (int j = 0; j < 2; ++j) {          // V^T frags: elems V[kk*32+lg*4+half*16+e][of*16+lm]
    int f = w + j * 4, kk = f >> 2, of = f & 3;
    int col = of * 16 + lm;
    bf16x8 a;
    #pragma unroll
    for (int half = 0; half < 2; ++half)
      #pragma unroll
      for (int e = 0; e < 4; ++e)
        a[half * 4 + e] = vt[(kk * 32 + lg * 4 + half * 16 + e) * 68 + col];
    *(bf16x8*)&Vb[obase + (size_t)(f * 64 + lane) * 8] = a;
  }
}

// ---------------------------------------------------------------------------
// Flash attention, 2-phase pipelined. One block = (b, h, 64 q-rows).
// K/V staged via linear global_load_lds (double-buffered); bias straight to
// registers (double-buffered), matching the S^T D-fragment layout per lane.
// ---------------------------------------------------------------------------
__device__ __forceinline__ void attn_tile(const short* kb, const short* vb,
                                          const f32x4* br, const bf16x8* qf,
                                          int lane, float& M, float& L, f32x4* o) {
  const f32x4 zero4 = {0.f, 0.f, 0.f, 0.f};
  f32x4 sacc[4];
  #pragma unroll
  for (int i = 0; i < 4; ++i) sacc[i] = zero4;
  #pragma unroll
  for (int kk = 0; kk < 2; ++kk)
    #pragma unroll
    for (int mf = 0; mf < 4; ++mf) {
      bf16x8 a = *(const bf16x8*)&kb[(kk * 4 + mf) * 512 + lane * 8];
      sacc[mf] = MFMA_BF16(a, qf[kk], sacc[mf], 0, 0, 0);
    }
  float p[4][4];
  float tmax = -__builtin_inff();
  #pragma unroll
  for (int mf = 0; mf < 4; ++mf)
    #pragma unroll
    for (int j = 0; j < 4; ++j) {
      float tv = (sacc[mf][j] + br[mf][j]) * SL;   // log2-domain logits
      p[mf][j] = tv;
      tmax = fmaxf(tmax, tv);
    }
  tmax = fmaxf(tmax, __shfl_xor(tmax, 16, 64));
  tmax = fmaxf(tmax, __shfl_xor(tmax, 32, 64));
  const float Mn = fmaxf(M, tmax);
  const float alpha = exp2f(M - Mn);
  float psum = 0.f;
  #pragma unroll
  for (int mf = 0; mf < 4; ++mf)
    #pragma unroll
    for (int j = 0; j < 4; ++j) {
      float e = exp2f(p[mf][j] - Mn);
      p[mf][j] = e;
      psum += e;
    }
  psum += __shfl_xor(psum, 16, 64);
  psum += __shfl_xor(psum, 32, 64);
  L = L * alpha + psum;
  M = Mn;
  #pragma unroll
  for (int of = 0; of < 4; ++of) {
    o[of][0] *= alpha; o[of][1] *= alpha; o[of][2] *= alpha; o[of][3] *= alpha;
  }
  bf16x8 pb[2];
  #pragma unroll
  for (int kk = 0; kk < 2; ++kk)
    #pragma unroll
    for (int j = 0; j < 8; ++j)
      pb[kk][j] = f2bf(p[kk * 2 + (j >> 2)][j & 3]);
  #pragma unroll
  for (int kk = 0; kk < 2; ++kk)
    #pragma unroll
    for (int of = 0; of < 4; ++of) {
      bf16x8 a = *(const bf16x8*)&vb[(kk * 4 + of) * 512 + lane * 8];
      o[of] = MFMA_BF16(a, pb[kk], o[of], 0, 0, 0);
    }
}

__global__ __launch_bounds__(256, 4)
void attn_fused(const float* __restrict__ Qg, const float* __restrict__ Bg,
                const short* __restrict__ Kb, const short* __restrict__ Vb,
                short* __restrict__ comb) {
  __shared__ __attribute__((aligned(16))) short smem[16384]; // k0,k1,v0,v1 @ 0,4096,8192,12288
  const int bid = blockIdx.x;
  // XCD pairing: dispatch slots s and s+8 (same XCD, adjacent rounds) get the
  // b=0 / b=1 blocks of the same (h, q-tile) -> bias tile L2-shared.
  const int rr = bid >> 4, x = bid & 15;
  const int pairidx = rr * 8 + (x & 7);
  const int b = x >> 3;
  const int h = pairidx >> 5, qt = pairidx & 31;
  const int q0 = qt * 64;
  const int t = threadIdx.x, lane = t & 63, w = t >> 6;
  const int lg = lane >> 4, lm = lane & 15;

  // Q fragment (B operand of S^T = K*Q^T): lane's query col = w*16+lm
  bf16x8 qf[2];
  {
    const float* qp = Qg + ((size_t)(b * S + q0 + w * 16 + lm)) * D + h * HD;
    #pragma unroll
    for (int kk = 0; kk < 2; ++kk)
      #pragma unroll
      for (int j = 0; j < 8; ++j)
        qf[kk][j] = f2bf(qp[kk * 32 + (j >> 2) * 16 + lg * 4 + (j & 3)]);
  }

  const short* Kt = Kb + ((size_t)(b * H + h) * NT) * 4096;
  const short* Vt = Vb + ((size_t)(b * H + h) * NT) * 4096;
  const float* bp = Bg + ((size_t)(h * S + q0 + w * 16 + lm)) * S + lg * 4;

  const f32x4 zero4 = {0.f, 0.f, 0.f, 0.f};
  f32x4 o[4];
  #pragma unroll
  for (int i = 0; i < 4; ++i) o[i] = zero4;
  float M = -__builtin_inff(), L = 0.f;

#define STAGE(tile, kdst, vdst)                                        \
  {                                                                    \
    const short* kg_ = Kt + (size_t)(tile) * 4096;                     \
    const short* vg_ = Vt + (size_t)(tile) * 4096;                     \
    _Pragma("unroll")                                                  \
    for (int r_ = 0; r_ < 2; ++r_) {                                   \
      GLDS16(kg_ + (size_t)((r_ * 4 + w) * 64 + lane) * 8,             \
             (kdst) + (r_ * 4 + w) * 512);                             \
      GLDS16(vg_ + (size_t)((r_ * 4 + w) * 64 + lane) * 8,             \
             (vdst) + (r_ * 4 + w) * 512);                             \
    }                                                                  \
  }

#define BLOAD(dst, tile)                                               \
  {                                                                    \
    const float* bq_ = bp + (tile) * 64;                               \
    dst[0] = *(const f32x4*)(bq_);                                     \
    dst[1] = *(const f32x4*)(bq_ + 16);                                \
    dst[2] = *(const f32x4*)(bq_ + 32);                                \
    dst[3] = *(const f32x4*)(bq_ + 48);                                \
  }

  f32x4 biasA[4], biasB[4];
  STAGE(0, smem, smem + 8192);
  BLOAD(biasA, 0);
  __syncthreads();

  for (int tt = 0; tt < NT; tt += 2) {
    // even tile: buffers 0, bias A; prefetch tile tt+1 into buffers 1 / bias B
    STAGE(tt + 1, smem + 4096, smem + 12288);
    BLOAD(biasB, tt + 1);
    attn_tile(smem, smem + 8192, biasA, qf, lane, M, L, o);
    __syncthreads();
    // odd tile: buffers 1, bias B; prefetch tile tt+2 into buffers 0 / bias A
    if (tt + 2 < NT) {
      STAGE(tt + 2, smem, smem + 8192);
      BLOAD(biasA, tt + 2);
    }
    attn_tile(smem + 4096, smem + 12288, biasB, qf, lane, M, L, o);
    __syncthreads();
  }

  // normalize, transpose O^T -> [q][d] through LDS, coalesced bf16 store
  const float invL = 1.f / L;
  short* out_lds = smem;                 // [64 q][64 d], stride 72
  #pragma unroll
  for (int of = 0; of < 4; ++of)
    #pragma unroll
    for (int j = 0; j < 4; ++j)
      out_lds[(w * 16 + lm) * 72 + of * 16 + lg * 4 + j] = f2bf(o[of][j] * invL);
  __syncthreads();
  #pragma unroll
  for (int it = 0; it < 2; ++it) {
    int idx = it * 256 + t;
    int r = idx >> 3, seg = idx & 7;
    u32x4 u = *(const u32x4*)&out_lds[r * 72 + seg * 8];
    *(u32x4*)&comb[((size_t)(b * S + q0 + r)) * D + h * HD + seg * 8] = u;
  }
#undef STAGE
#undef BLOAD
}

// ---------------------------------------------------------------------------
// w_out [k][n] f32 -> Wt [n][k] bf16
// ---------------------------------------------------------------------------
__global__ __launch_bounds__(256)
void wt_kernel(const float* __restrict__ W, short* __restrict__ Wt) {
  __shared__ __attribute__((aligned(16))) short tile[64 * 72];
  const int n0 = blockIdx.x * 64, k0 = blockIdx.y * 64;
  const int t = threadIdx.x;
  #pragma unroll
  for (int i = 0; i < 4; ++i) {
    int idx = i * 256 + t;
    int r  = idx >> 4, c4 = (idx & 15) * 4;
    float4 wv = *(const float4*)(W + (size_t)(k0 + r) * D + n0 + c4);
    tile[(c4 + 0) * 72 + r] = f2bf(wv.x);
    tile[(c4 + 1) * 72 + r] = f2bf(wv.y);
    tile[(c4 + 2) * 72 + r] = f2bf(wv.z);
    tile[(c4 + 3) * 72 + r] = f2bf(wv.w);
  }
  __syncthreads();
  #pragma unroll
  for (int it = 0; it < 2; ++it) {
    int idx = it * 256 + t;
    int r = idx >> 3, seg = idx & 7;
    u32x4 u = *(const u32x4*)&tile[r * 72 + seg * 8];
    *(u32x4*)&Wt[(size_t)(n0 + r) * D + k0 + seg * 8] = u;
  }
}

// ---------------------------------------------------------------------------
// C[4096,1024] f32 = A[4096,1024] bf16 * Wt^T ; Wt is [n][k] bf16.
// ---------------------------------------------------------------------------
__global__ __launch_bounds__(256, 2)
void proj_gemm(const short* __restrict__ A, const short* __restrict__ Bt,
               float* __restrict__ C) {
  constexpr int AST = 80;
  __shared__ __attribute__((aligned(16))) short a_lds[128 * AST];
  __shared__ __attribute__((aligned(16))) short b_lds[128 * AST];
  const int m0 = blockIdx.x * 128, n0 = blockIdx.y * 128;
  const int t = threadIdx.x, lane = t & 63, w = t >> 6;
  const int lg = lane >> 4, lm = lane & 15;
  const int wm = w >> 1, wn = w & 1;

  const f32x4 zero4 = {0.f, 0.f, 0.f, 0.f};
  f32x4 acc[4][4];
  #pragma unroll
  for (int i = 0; i < 4; ++i)
    #pragma unroll
    for (int j = 0; j < 4; ++j) acc[i][j] = zero4;

  for (int kt = 0; kt < D; kt += 64) {
    __syncthreads();
    #pragma unroll
    for (int i = 0; i < 4; ++i) {
      int idx = i * 256 + t;
      int r = idx >> 3, seg = idx & 7;
      u32x4 av = *(const u32x4*)&A [(size_t)(m0 + r) * D + kt + seg * 8];
      *(u32x4*)&a_lds[r * AST + seg * 8] = av;
      u32x4 bv = *(const u32x4*)&Bt[(size_t)(n0 + r) * D + kt + seg * 8];
      *(u32x4*)&b_lds[r * AST + seg * 8] = bv;
    }
    __syncthreads();
    #pragma unroll
    for (int kk = 0; kk < 2; ++kk) {
      bf16x8 af[4], bfr[4];
      #pragma unroll
      for (int mf = 0; mf < 4; ++mf) {
        const short* ar = &a_lds[(wm * 64 + mf * 16 + lm) * AST + kk * 32 + lg * 4];
        s16x4 c0 = *(const s16x4*)(ar);
        s16x4 c1 = *(const s16x4*)(ar + 16);
        af[mf][0]=c0[0]; af[mf][1]=c0[1]; af[mf][2]=c0[2]; af[mf][3]=c0[3];
        af[mf][4]=c1[0]; af[mf][5]=c1[1]; af[mf][6]=c1[2]; af[mf][7]=c1[3];
      }
      #pragma unroll
      for (int nf = 0; nf < 4; ++nf) {
        const short* br = &b_lds[(wn * 64 + nf * 16 + lm) * AST + kk * 32 + lg * 4];
        s16x4 c0 = *(const s16x4*)(br);
        s16x4 c1 = *(const s16x4*)(br + 16);
        bfr[nf][0]=c0[0]; bfr[nf][1]=c0[1]; bfr[nf][2]=c0[2]; bfr[nf][3]=c0[3];
        bfr[nf][4]=c1[0]; bfr[nf][5]=c1[1]; bfr[nf][6]=c1[2]; bfr[nf][7]=c1[3];
      }
      #pragma unroll
      for (int mf = 0; mf < 4; ++mf)
        #pragma unroll
        for (int nf = 0; nf < 4; ++nf)
          acc[mf][nf] = MFMA_BF16(af[mf], bfr[nf], acc[mf][nf], 0, 0, 0);
    }
  }
  #pragma unroll
  for (int mf = 0; mf < 4; ++mf)
    #pragma unroll
    for (int j = 0; j < 4; ++j)
      #pragma unroll
      for (int nf = 0; nf < 4; ++nf)
        C[(size_t)(m0 + wm * 64 + mf * 16 + lg * 4 + j) * D +
          n0 + wn * 64 + nf * 16 + lm] = acc[mf][nf][j];
}

extern "C" void kernel_launch(void* const* d_in, const int* in_sizes, int n_in,
                              void* d_out, int out_size, void* d_ws, size_t ws_size,
                              hipStream_t stream) {
  const float* Qg = (const float*)d_in[0];
  const float* Kg = (const float*)d_in[1];
  const float* Vg = (const float*)d_in[2];
  const float* Bg = (const float*)d_in[3];
  const float* Wg = (const float*)d_in[4];
  float* out = (float*)d_out;

  short* comb = (short*)d_ws;                          //  8 MB bf16 [4096][1024]
  short* Wt   = comb + (size_t)(2 * S) * D;            //  2 MB bf16 [1024][1024]
  short* Kb   = Wt   + (size_t)D * D;                  //  8 MB fragment-major K
  short* Vb   = Kb   + (size_t)2 * H * NT * 4096;      //  8 MB fragment-major V^T

  kv_prep<<<dim3(NT, H, 2), 256, 0, stream>>>(Kg, Vg, Kb, Vb);
  wt_kernel<<<dim3(D / 64, D / 64), 256, 0, stream>>>(Wg, Wt);
  attn_fused<<<dim3(1024), 256, 0, stream>>>(Qg, Bg, Kb, Vb, comb);
  proj_gemm<<<dim3((2 * S) / 128, D / 128), 256, 0, stream>>>(comb, Wt, out);
}

// Round 3
// 150.586 us; speedup vs baseline: 1.8352x; 1.1895x over previous
//
#include <hip/hip_runtime.h>

typedef float  f32x4  __attribute__((ext_vector_type(4)));
typedef short  bf16x8 __attribute__((ext_vector_type(8)));
typedef short  s16x4  __attribute__((ext_vector_type(4)));
typedef unsigned int u32x4 __attribute__((ext_vector_type(4)));

#define MFMA_BF16 __builtin_amdgcn_mfma_f32_16x16x32_bf16

// native RNE f32->bf16 (compiler fuses pairs into v_cvt_pk_bf16_f32)
__device__ __forceinline__ short f2bf(float f) {
  __bf16 h = (__bf16)f;
  return __builtin_bit_cast(short, h);
}

constexpr int S = 2048, D = 1024, H = 16, HD = 64;
constexpr int NT = S / 64;                 // 32 kv tiles
constexpr float SCALE = 0.125f;            // 1/sqrt(64)
constexpr float L2E = 1.44269504f;
constexpr float SL = SCALE * L2E;          // logits -> log2 domain in one mul

// async 16B global->LDS (lds dest wave-uniform; HW adds lane*16)
#define GLDS16(g, l) __builtin_amdgcn_global_load_lds( \
    (const __attribute__((address_space(1))) unsigned*)(g), \
    (__attribute__((address_space(3))) unsigned*)(l), 16, 0, 0)

#define WAITV(n) asm volatile("s_waitcnt vmcnt(" #n ")" ::: "memory")
#define SBAR()   __builtin_amdgcn_s_barrier()

// ---------------------------------------------------------------------------
// K/V prep: f32 [B,S,D] head-slices -> bf16 fragment-major tiles.
// Per (b,h,kv-tile): 8 K-frags (f=kk*4+mf) and 8 V^T-frags (f=kk*4+of),
// each frag = 64 lanes x 8 bf16 contiguous -> tile block = 4096 shorts (8KB).
// ---------------------------------------------------------------------------
__global__ __launch_bounds__(256)
void kv_prep(const float* __restrict__ Kg, const float* __restrict__ Vg,
             short* __restrict__ Kb, short* __restrict__ Vb) {
  const int tile = blockIdx.x, h = blockIdx.y, b = blockIdx.z;
  const int t = threadIdx.x, lane = t & 63, w = t >> 6;
  const int lg = lane >> 4, lm = lane & 15;
  __shared__ short kt[64 * 68], vt[64 * 68];
  const float* kp = Kg + ((size_t)(b * S + tile * 64)) * D + h * HD;
  const float* vp = Vg + ((size_t)(b * S + tile * 64)) * D + h * HD;
  #pragma unroll
  for (int i = 0; i < 4; ++i) {
    int idx = i * 256 + t, r = idx >> 4, c4 = (idx & 15) * 4;
    float4 k4 = *(const float4*)(kp + (size_t)r * D + c4);
    s16x4 ks; ks[0]=f2bf(k4.x); ks[1]=f2bf(k4.y); ks[2]=f2bf(k4.z); ks[3]=f2bf(k4.w);
    *(s16x4*)&kt[r * 68 + c4] = ks;
    float4 v4 = *(const float4*)(vp + (size_t)r * D + c4);
    s16x4 vs; vs[0]=f2bf(v4.x); vs[1]=f2bf(v4.y); vs[2]=f2bf(v4.z); vs[3]=f2bf(v4.w);
    *(s16x4*)&vt[r * 68 + c4] = vs;
  }
  __syncthreads();
  const size_t obase = ((size_t)((b * H + h) * NT + tile)) * 4096;
  #pragma unroll
  for (int j = 0; j < 2; ++j) {          // K frags
    int f = w + j * 4, kk = f >> 2, mf = f & 3;
    int row = mf * 16 + lm, col = kk * 32 + lg * 4;
    s16x4 c0 = *(const s16x4*)&kt[row * 68 + col];
    s16x4 c1 = *(const s16x4*)&kt[row * 68 + col + 16];
    bf16x8 a;
    a[0]=c0[0]; a[1]=c0[1]; a[2]=c0[2]; a[3]=c0[3];
    a[4]=c1[0]; a[5]=c1[1]; a[6]=c1[2]; a[7]=c1[3];
    *(bf16x8*)&Kb[obase + (size_t)(f * 64 + lane) * 8] = a;
  }
  #pragma unroll
  for (int j = 0; j < 2; ++j) {          // V^T frags
    int f = w + j * 4, kk = f >> 2, of = f & 3;
    int col = of * 16 + lm;
    bf16x8 a;
    #pragma unroll
    for (int half = 0; half < 2; ++half)
      #pragma unroll
      for (int e = 0; e < 4; ++e)
        a[half * 4 + e] = vt[(kk * 32 + lg * 4 + half * 16 + e) * 68 + col];
    *(bf16x8*)&Vb[obase + (size_t)(f * 64 + lane) * 8] = a;
  }
}

// ---------------------------------------------------------------------------
// Flash attention, counted-vmcnt 2-phase pipeline (raw s_barrier, never
// vmcnt(0) mid-loop). One block = (b, h, 64 q-rows).
// ---------------------------------------------------------------------------
__device__ __forceinline__ void attn_tile(const short* kb, const short* vb,
                                          const f32x4* br, const bf16x8* qf,
                                          int lane, float& M, float& L, f32x4* o) {
  const f32x4 zero4 = {0.f, 0.f, 0.f, 0.f};
  f32x4 sacc[4];
  #pragma unroll
  for (int i = 0; i < 4; ++i) sacc[i] = zero4;
  __builtin_amdgcn_s_setprio(1);
  #pragma unroll
  for (int kk = 0; kk < 2; ++kk)
    #pragma unroll
    for (int mf = 0; mf < 4; ++mf) {
      bf16x8 a = *(const bf16x8*)&kb[(kk * 4 + mf) * 512 + lane * 8];
      sacc[mf] = MFMA_BF16(a, qf[kk], sacc[mf], 0, 0, 0);
    }
  __builtin_amdgcn_s_setprio(0);
  float p[4][4];
  float tmax = -__builtin_inff();
  #pragma unroll
  for (int mf = 0; mf < 4; ++mf)
    #pragma unroll
    for (int j = 0; j < 4; ++j) {
      float tv = (sacc[mf][j] + br[mf][j]) * SL;   // log2-domain logits
      p[mf][j] = tv;
      tmax = fmaxf(tmax, tv);
    }
  tmax = fmaxf(tmax, __shfl_xor(tmax, 16, 64));
  tmax = fmaxf(tmax, __shfl_xor(tmax, 32, 64));
  const float Mn = fmaxf(M, tmax);
  const float alpha = exp2f(M - Mn);
  float psum = 0.f;
  #pragma unroll
  for (int mf = 0; mf < 4; ++mf)
    #pragma unroll
    for (int j = 0; j < 4; ++j) {
      float e = exp2f(p[mf][j] - Mn);
      p[mf][j] = e;
      psum += e;
    }
  psum += __shfl_xor(psum, 16, 64);
  psum += __shfl_xor(psum, 32, 64);
  L = L * alpha + psum;
  M = Mn;
  #pragma unroll
  for (int of = 0; of < 4; ++of) {
    o[of][0] *= alpha; o[of][1] *= alpha; o[of][2] *= alpha; o[of][3] *= alpha;
  }
  bf16x8 pb[2];
  #pragma unroll
  for (int kk = 0; kk < 2; ++kk)
    #pragma unroll
    for (int j = 0; j < 8; ++j)
      pb[kk][j] = f2bf(p[kk * 2 + (j >> 2)][j & 3]);
  __builtin_amdgcn_s_setprio(1);
  #pragma unroll
  for (int kk = 0; kk < 2; ++kk)
    #pragma unroll
    for (int of = 0; of < 4; ++of) {
      bf16x8 a = *(const bf16x8*)&vb[(kk * 4 + of) * 512 + lane * 8];
      o[of] = MFMA_BF16(a, pb[kk], o[of], 0, 0, 0);
    }
  __builtin_amdgcn_s_setprio(0);
}

__global__ __launch_bounds__(256, 4)
void attn_fused(const float* __restrict__ Qg, const float* __restrict__ Bg,
                const short* __restrict__ Kb, const short* __restrict__ Vb,
                short* __restrict__ comb) {
  __shared__ __attribute__((aligned(16))) short smem[16384]; // K0,K1,V0,V1 @ 0,4096,8192,12288
  const int bid = blockIdx.x;
  // XCD pairing: b=0/b=1 of the same (h,q-tile) land 8 dispatch slots apart
  const int rr = bid >> 4, x = bid & 15;
  const int pairidx = rr * 8 + (x & 7);
  const int b = x >> 3;
  const int h = pairidx >> 5, qt = pairidx & 31;
  const int q0 = qt * 64;
  const int t = threadIdx.x, lane = t & 63, w = t >> 6;
  const int lg = lane >> 4, lm = lane & 15;

  bf16x8 qf[2];
  {
    const float* qp = Qg + ((size_t)(b * S + q0 + w * 16 + lm)) * D + h * HD;
    #pragma unroll
    for (int kk = 0; kk < 2; ++kk)
      #pragma unroll
      for (int j = 0; j < 8; ++j)
        qf[kk][j] = f2bf(qp[kk * 32 + (j >> 2) * 16 + lg * 4 + (j & 3)]);
  }

  const short* Kt = Kb + ((size_t)(b * H + h) * NT) * 4096;
  const short* Vt = Vb + ((size_t)(b * H + h) * NT) * 4096;
  const float* bp = Bg + ((size_t)(h * S + q0 + w * 16 + lm)) * S + lg * 4;

  const f32x4 zero4 = {0.f, 0.f, 0.f, 0.f};
  f32x4 o[4];
  #pragma unroll
  for (int i = 0; i < 4; ++i) o[i] = zero4;
  float M = -__builtin_inff(), L = 0.f;

#define STAGE(tile, kdst, vdst)                                        \
  {                                                                    \
    const short* kg_ = Kt + (size_t)(tile) * 4096;                     \
    const short* vg_ = Vt + (size_t)(tile) * 4096;                     \
    _Pragma("unroll")                                                  \
    for (int r_ = 0; r_ < 2; ++r_) {                                   \
      GLDS16(kg_ + (size_t)((r_ * 4 + w) * 64 + lane) * 8,             \
             (kdst) + (r_ * 4 + w) * 512);                             \
      GLDS16(vg_ + (size_t)((r_ * 4 + w) * 64 + lane) * 8,             \
             (vdst) + (r_ * 4 + w) * 512);                             \
    }                                                                  \
  }

#define BLOAD(dst, tile)                                               \
  {                                                                    \
    const float* bq_ = bp + (tile) * 64;                               \
    dst[0] = *(const f32x4*)(bq_);                                     \
    dst[1] = *(const f32x4*)(bq_ + 16);                                \
    dst[2] = *(const f32x4*)(bq_ + 32);                                \
    dst[3] = *(const f32x4*)(bq_ + 48);                                \
  }

  f32x4 biasA[4], biasB[4];
  STAGE(0, smem, smem + 8192);
  BLOAD(biasA, 0);

  // per-iter: 8 vm ops issued (4 gload_lds + 4 bias dwordx4); vmcnt(8)
  // guarantees everything older (the tile we're about to compute) is done.
  for (int tt = 0; tt < NT; tt += 2) {
    SBAR();                               // all waves done reading K0/V0
    STAGE(tt + 1, smem + 4096, smem + 12288);
    BLOAD(biasB, tt + 1);
    WAITV(8);
    SBAR();
    attn_tile(smem, smem + 8192, biasA, qf, lane, M, L, o);
    SBAR();                               // all waves done reading K1/V1
    if (tt + 2 < NT) {
      STAGE(tt + 2, smem, smem + 8192);
      BLOAD(biasA, tt + 2);
      WAITV(8);
    } else {
      WAITV(0);
    }
    SBAR();
    attn_tile(smem + 4096, smem + 12288, biasB, qf, lane, M, L, o);
  }

  // normalize, transpose O^T -> [q][d] through LDS, coalesced bf16 store
  const float invL = 1.f / L;
  __syncthreads();
  short* out_lds = smem;                 // [64 q][64 d], stride 72
  #pragma unroll
  for (int of = 0; of < 4; ++of)
    #pragma unroll
    for (int j = 0; j < 4; ++j)
      out_lds[(w * 16 + lm) * 72 + of * 16 + lg * 4 + j] = f2bf(o[of][j] * invL);
  __syncthreads();
  #pragma unroll
  for (int it = 0; it < 2; ++it) {
    int idx = it * 256 + t;
    int r = idx >> 3, seg = idx & 7;
    u32x4 u = *(const u32x4*)&out_lds[r * 72 + seg * 8];
    *(u32x4*)&comb[((size_t)(b * S + q0 + r)) * D + h * HD + seg * 8] = u;
  }
#undef STAGE
#undef BLOAD
}

// ---------------------------------------------------------------------------
// w_out [k][n] f32 -> Wt [n][k] bf16
// ---------------------------------------------------------------------------
__global__ __launch_bounds__(256)
void wt_kernel(const float* __restrict__ W, short* __restrict__ Wt) {
  __shared__ __attribute__((aligned(16))) short tile[64 * 72];
  const int n0 = blockIdx.x * 64, k0 = blockIdx.y * 64;
  const int t = threadIdx.x;
  #pragma unroll
  for (int i = 0; i < 4; ++i) {
    int idx = i * 256 + t;
    int r  = idx >> 4, c4 = (idx & 15) * 4;
    float4 wv = *(const float4*)(W + (size_t)(k0 + r) * D + n0 + c4);
    tile[(c4 + 0) * 72 + r] = f2bf(wv.x);
    tile[(c4 + 1) * 72 + r] = f2bf(wv.y);
    tile[(c4 + 2) * 72 + r] = f2bf(wv.z);
    tile[(c4 + 3) * 72 + r] = f2bf(wv.w);
  }
  __syncthreads();
  #pragma unroll
  for (int it = 0; it < 2; ++it) {
    int idx = it * 256 + t;
    int r = idx >> 3, seg = idx & 7;
    u32x4 u = *(const u32x4*)&tile[r * 72 + seg * 8];
    *(u32x4*)&Wt[(size_t)(n0 + r) * D + k0 + seg * 8] = u;
  }
}

// ---------------------------------------------------------------------------
// proj: C[4096,1024] f32 = A[4096,1024] bf16 * Wt^T ; Wt is [n][k] bf16.
// 128x64 tile, BK=64, grid 32x16 = 512 blocks (2/CU). global_load_lds
// staging with both-sides 16B-unit XOR swizzle; counted-vmcnt 2-phase.
// LDS tile rows are 128B; slot (row, unit c) holds global unit c^(row&7);
// reads XOR the same -> conflict-free.
// ---------------------------------------------------------------------------
__device__ __forceinline__ bf16x8 ld_frag_swz(const short* base, int row, int kk, int lg) {
  const char* rp = (const char*)base + row * 128 + (lg & 1) * 8;
  int u0 = kk * 4 + (lg >> 1);
  int f  = row & 7;
  s16x4 c0 = *(const s16x4*)(rp + ((u0 ^ f) << 4));
  s16x4 c1 = *(const s16x4*)(rp + (((u0 + 2) ^ f) << 4));
  bf16x8 a;
  a[0]=c0[0]; a[1]=c0[1]; a[2]=c0[2]; a[3]=c0[3];
  a[4]=c1[0]; a[5]=c1[1]; a[6]=c1[2]; a[7]=c1[3];
  return a;
}

__global__ __launch_bounds__(256, 2)
void proj_gemm(const short* __restrict__ A, const short* __restrict__ Bt,
               float* __restrict__ C) {
  __shared__ __attribute__((aligned(16))) short a_lds[2][8192]; // 128x64 each
  __shared__ __attribute__((aligned(16))) short b_lds[2][4096]; //  64x64 each
  const int m0 = blockIdx.x * 128, n0 = blockIdx.y * 64;
  const int t = threadIdx.x, lane = t & 63, w = t >> 6;
  const int lg = lane >> 4, lm = lane & 15;
  const int srow = lane >> 3;                    // staging row-in-chunk
  const int sunit = (lane & 7) ^ srow;           // pre-swizzled source unit

  const f32x4 zero4 = {0.f, 0.f, 0.f, 0.f};
  f32x4 acc[2][4];
  #pragma unroll
  for (int i = 0; i < 2; ++i)
    #pragma unroll
    for (int j = 0; j < 4; ++j) acc[i][j] = zero4;

#define PSTAGE(ks, ab, bb)                                                  \
  {                                                                         \
    const short* ag_ = A  + (size_t)m0 * D + (ks) * 64;                     \
    const short* bg_ = Bt + (size_t)n0 * D + (ks) * 64;                     \
    _Pragma("unroll")                                                       \
    for (int i_ = 0; i_ < 4; ++i_) {                                        \
      int j_ = w * 4 + i_;                                                  \
      GLDS16(ag_ + (size_t)(j_ * 8 + srow) * D + sunit * 8, (ab) + j_ * 512); \
    }                                                                       \
    _Pragma("unroll")                                                       \
    for (int i_ = 0; i_ < 2; ++i_) {                                        \
      int j_ = w * 2 + i_;                                                  \
      GLDS16(bg_ + (size_t)(j_ * 8 + srow) * D + sunit * 8, (bb) + j_ * 512); \
    }                                                                       \
  }

#define PCOMPUTE(ab, bb)                                                    \
  {                                                                         \
    _Pragma("unroll")                                                       \
    for (int kk = 0; kk < 2; ++kk) {                                        \
      bf16x8 af0 = ld_frag_swz(ab, w * 32 + lm, kk, lg);                    \
      bf16x8 af1 = ld_frag_swz(ab, w * 32 + 16 + lm, kk, lg);               \
      bf16x8 bf0 = ld_frag_swz(bb, lm, kk, lg);                             \
      bf16x8 bf1 = ld_frag_swz(bb, 16 + lm, kk, lg);                        \
      bf16x8 bf2 = ld_frag_swz(bb, 32 + lm, kk, lg);                        \
      bf16x8 bf3 = ld_frag_swz(bb, 48 + lm, kk, lg);                        \
      __builtin_amdgcn_s_setprio(1);                                        \
      acc[0][0] = MFMA_BF16(af0, bf0, acc[0][0], 0, 0, 0);                  \
      acc[0][1] = MFMA_BF16(af0, bf1, acc[0][1], 0, 0, 0);                  \
      acc[0][2] = MFMA_BF16(af0, bf2, acc[0][2], 0, 0, 0);                  \
      acc[0][3] = MFMA_BF16(af0, bf3, acc[0][3], 0, 0, 0);                  \
      acc[1][0] = MFMA_BF16(af1, bf0, acc[1][0], 0, 0, 0);                  \
      acc[1][1] = MFMA_BF16(af1, bf1, acc[1][1], 0, 0, 0);                  \
      acc[1][2] = MFMA_BF16(af1, bf2, acc[1][2], 0, 0, 0);                  \
      acc[1][3] = MFMA_BF16(af1, bf3, acc[1][3], 0, 0, 0);                  \
      __builtin_amdgcn_s_setprio(0);                                        \
    }                                                                       \
  }

  PSTAGE(0, a_lds[0], b_lds[0]);
  for (int ks = 0; ks < 16; ks += 2) {
    SBAR();
    PSTAGE(ks + 1, a_lds[1], b_lds[1]);
    WAITV(6);
    SBAR();
    PCOMPUTE(a_lds[0], b_lds[0]);
    SBAR();
    if (ks + 2 < 16) {
      PSTAGE(ks + 2, a_lds[0], b_lds[0]);
      WAITV(6);
    } else {
      WAITV(0);
    }
    SBAR();
    PCOMPUTE(a_lds[1], b_lds[1]);
  }

  #pragma unroll
  for (int mf = 0; mf < 2; ++mf)
    #pragma unroll
    for (int j = 0; j < 4; ++j)
      #pragma unroll
      for (int nf = 0; nf < 4; ++nf)
        C[(size_t)(m0 + w * 32 + mf * 16 + lg * 4 + j) * D +
          n0 + nf * 16 + lm] = acc[mf][nf][j];
#undef PSTAGE
#undef PCOMPUTE
}

extern "C" void kernel_launch(void* const* d_in, const int* in_sizes, int n_in,
                              void* d_out, int out_size, void* d_ws, size_t ws_size,
                              hipStream_t stream) {
  const float* Qg = (const float*)d_in[0];
  const float* Kg = (const float*)d_in[1];
  const float* Vg = (const float*)d_in[2];
  const float* Bg = (const float*)d_in[3];
  const float* Wg = (const float*)d_in[4];
  float* out = (float*)d_out;

  short* comb = (short*)d_ws;                          //  8 MB bf16 [4096][1024]
  short* Wt   = comb + (size_t)(2 * S) * D;            //  2 MB bf16 [1024][1024]
  short* Kb   = Wt   + (size_t)D * D;                  //  8 MB fragment-major K
  short* Vb   = Kb   + (size_t)2 * H * NT * 4096;      //  8 MB fragment-major V^T

  kv_prep<<<dim3(NT, H, 2), 256, 0, stream>>>(Kg, Vg, Kb, Vb);
  wt_kernel<<<dim3(D / 64, D / 64), 256, 0, stream>>>(Wg, Wt);
  attn_fused<<<dim3(1024), 256, 0, stream>>>(Qg, Bg, Kb, Vb, comb);
  proj_gemm<<<dim3(32, 16), 256, 0, stream>>>(comb, Wt, out);
}